// Round 1
// baseline (784.616 us; speedup 1.0000x reference)
//
#include <hip/hip_runtime.h>
#include <stdint.h>

typedef short bf16x8 __attribute__((ext_vector_type(8)));
typedef float f32x4 __attribute__((ext_vector_type(4)));
typedef float f32x16 __attribute__((ext_vector_type(16)));
typedef unsigned short u16;
typedef unsigned int u32;

__device__ __forceinline__ u16 f2bf(float f) {
    u32 x = __float_as_uint(f);
    x += 0x7fffu + ((x >> 16) & 1u);
    return (u16)(x >> 16);
}
__device__ __forceinline__ u32 pack_bf2(float a, float b) {
    return (u32)f2bf(a) | ((u32)f2bf(b) << 16);
}

union Frag4 { u32 u[4]; bf16x8 v; };

// ---------------- f32 -> bf16 cast, 8 elems/thread (G13: vectorized) --------
__global__ void cvt_f32_bf16(const float* __restrict__ in, u16* __restrict__ out, long n8) {
    long stride = (long)gridDim.x * blockDim.x;
    for (long i = (long)blockIdx.x * blockDim.x + threadIdx.x; i < n8; i += stride) {
        const float4* p = (const float4*)(in + i * 8);
        float4 a = p[0], b = p[1];
        uint4 o;
        o.x = pack_bf2(a.x, a.y);
        o.y = pack_bf2(a.z, a.w);
        o.z = pack_bf2(b.x, b.y);
        o.w = pack_bf2(b.z, b.w);
        ((uint4*)out)[i] = o;
    }
}

// ---------------- bf16 NT GEMM: out = A * B^T + bias ------------------------
// A [M,K] bf16 row-major, B [N,K] bf16 row-major (both K contiguous).
// 128x128 tile, BK=64, 4 waves (2x2 of 64x64), mfma_f32_16x16x32_bf16.
// LDS XOR-swizzle byte ^= ((row&7)<<4) on both write and read (G4).
template<int OBF>
__global__ __launch_bounds__(256) void gemm_nt(
    const u16* __restrict__ A, const u16* __restrict__ B,
    const float* __restrict__ bias, void* __restrict__ out,
    int K, int ldo)
{
    __shared__ u16 lA[128 * 64];
    __shared__ u16 lB[128 * 64];
    const int tid  = threadIdx.x;
    const int lane = tid & 63;
    const int w    = tid >> 6;
    const int wm = (w >> 1) * 64, wn = (w & 1) * 64;
    const int bm = blockIdx.x * 128, bn = blockIdx.y * 128;

    f32x4 acc[4][4];
#pragma unroll
    for (int i = 0; i < 4; ++i)
#pragma unroll
        for (int j = 0; j < 4; ++j)
#pragma unroll
            for (int r = 0; r < 4; ++r) acc[i][j][r] = 0.f;

    for (int k0 = 0; k0 < K; k0 += 64) {
        uint4 ra[4], rb[4];
#pragma unroll
        for (int i = 0; i < 4; ++i) {
            u32 o = i * 4096 + tid * 16;         // byte offset into 16KB tile
            u32 r = o >> 7, c = (o & 127) >> 1;  // row, elem col
            ra[i] = *(const uint4*)(A + (size_t)(bm + r) * K + k0 + c);
            rb[i] = *(const uint4*)(B + (size_t)(bn + r) * K + k0 + c);
        }
        __syncthreads();
#pragma unroll
        for (int i = 0; i < 4; ++i) {
            u32 o = i * 4096 + tid * 16;
            u32 r = o >> 7, byt = o & 127;
            u32 sb = byt ^ ((r & 7) << 4);       // write-side swizzle
            *(uint4*)((char*)lA + r * 128 + sb) = ra[i];
            *(uint4*)((char*)lB + r * 128 + sb) = rb[i];
        }
        __syncthreads();
#pragma unroll
        for (int kk = 0; kk < 2; ++kk) {
            bf16x8 af[4], bfr[4];
#pragma unroll
            for (int f = 0; f < 4; ++f) {
                u32 m = wm + f * 16 + (lane & 15);
                u32 byt = (u32)(kk * 64 + ((lane >> 4) * 16));
                af[f]  = *(const bf16x8*)((const char*)lA + m * 128 + (byt ^ ((m & 7) << 4)));
                u32 n = wn + f * 16 + (lane & 15);
                bfr[f] = *(const bf16x8*)((const char*)lB + n * 128 + (byt ^ ((n & 7) << 4)));
            }
#pragma unroll
            for (int i = 0; i < 4; ++i)
#pragma unroll
                for (int j = 0; j < 4; ++j)
                    acc[i][j] = __builtin_amdgcn_mfma_f32_16x16x32_bf16(af[i], bfr[j], acc[i][j], 0, 0, 0);
        }
    }
    // epilogue: C/D layout col=lane&15, row=(lane>>4)*4+reg (m89-verified)
#pragma unroll
    for (int i = 0; i < 4; ++i) {
        int m0 = bm + wm + i * 16 + ((lane >> 4) << 2);
#pragma unroll
        for (int j = 0; j < 4; ++j) {
            int n = bn + wn + j * 16 + (lane & 15);
            float bv = bias[n];
#pragma unroll
            for (int r = 0; r < 4; ++r) {
                float v = acc[i][j][r] + bv;
                if constexpr (OBF != 0)
                    ((u16*)out)[(size_t)(m0 + r) * ldo + n] = f2bf(v);
                else
                    ((float*)out)[(size_t)(m0 + r) * ldo + n] = v;
            }
        }
    }
}

// ---------------- causal flash attention ------------------------------------
// qkv [B*T, 6144] bf16 (cols: Q 0..2047, K 2048..4095, V 4096..6143; head h at
// h*128). One block = (b, h, 128 q rows); 4 waves x 32 q rows each; KVBLK=32.
// Swapped QK^T: S^T = mfma32(K,Q) so lane owns q = lane&31's softmax state.
// Swapped PV: O^T = mfma32(V^T, P^T) so online rescale is lane-uniform.
__global__ __launch_bounds__(256) void attn_fwd(
    const u16* __restrict__ qkv, u16* __restrict__ obuf)
{
    __shared__ u16 lK[32 * 128];  // swizzled rows (256B)
    __shared__ u16 lV[32 * 128];  // linear
    const int tid  = threadIdx.x;
    const int lane = tid & 63;
    const int w    = tid >> 6;
    const int g    = lane >> 5;

    // load-balance: pair short (qt) with long (15-qt) tiles across the grid
    int qi = blockIdx.x >> 5;
    int bh = blockIdx.x & 31;
    int qt = (qi < 8) ? qi : 23 - qi;
    int b = bh >> 4, h = bh & 15;
    const size_t rowbase = (size_t)b * 2048;
    const int qb = qt * 128;
    const int qw = qb + w * 32;
    const int q  = qw + (lane & 31);

    // Q as MFMA B-operand frags: qf[ch][j] = Q[q][ch*16 + g*8 + j]
    bf16x8 qf[8];
    {
        const u16* qrow = qkv + (rowbase + q) * 6144 + h * 128;
#pragma unroll
        for (int ch = 0; ch < 8; ++ch)
            qf[ch] = *(const bf16x8*)(qrow + ch * 16 + g * 8);
    }

    f32x16 acc[4];
#pragma unroll
    for (int dt = 0; dt < 4; ++dt)
#pragma unroll
        for (int r = 0; r < 16; ++r) acc[dt][r] = 0.f;

    float m_run = -1e30f, l_run = 0.f;
    const float C2 = 0.08838834764831845f * 1.44269504088896341f; // scale*log2e
    const int nt = qb / 32 + 4;

    for (int t = 0; t < nt; ++t) {
        const int kb = t * 32;
        uint4 rk[2], rv[2];
#pragma unroll
        for (int i = 0; i < 2; ++i) {
            u32 o = i * 4096 + tid * 16;
            u32 r = o >> 8, c = (o & 255) >> 1;
            const u16* src = qkv + (rowbase + kb + r) * 6144 + h * 128 + c;
            rk[i] = *(const uint4*)(src + 2048);
            rv[i] = *(const uint4*)(src + 4096);
        }
        __syncthreads();
#pragma unroll
        for (int i = 0; i < 2; ++i) {
            u32 o = i * 4096 + tid * 16;
            u32 r = o >> 8, byt = o & 255;
            *(uint4*)((char*)lK + r * 256 + (byt ^ ((r & 15) << 4))) = rk[i];
            *(uint4*)((char*)lV + o) = rv[i];
        }
        __syncthreads();

        if (kb <= qw + 31) {
            // S^T tile [32k x 32q]; 8 d-chunks of 16
            f32x16 s;
#pragma unroll
            for (int r = 0; r < 16; ++r) s[r] = 0.f;
#pragma unroll
            for (int ch = 0; ch < 8; ++ch) {
                u32 r = lane & 31;
                u32 byt = (u32)(ch * 32 + g * 16);
                bf16x8 kf = *(const bf16x8*)((const char*)lK + r * 256 + (byt ^ ((r & 15) << 4)));
                s = __builtin_amdgcn_mfma_f32_32x32x16_bf16(kf, qf[ch], s, 0, 0, 0);
            }
            // lane holds S^T[k'][q=lane&31], k'(r) = (r&3)+8*(r>>2)+4*g
            float p[16];
            float tmax = -1e30f;
#pragma unroll
            for (int r = 0; r < 16; ++r) {
                int kg = kb + (r & 3) + 8 * (r >> 2) + 4 * g;
                float v = s[r];
                if (kg > q) v = -1e30f;     // causal mask
                p[r] = v;
                tmax = fmaxf(tmax, v);
            }
            tmax = fmaxf(tmax, __shfl_xor(tmax, 32)); // other k-half
            float mnew  = fmaxf(m_run, tmax);
            float alpha = exp2f((m_run - mnew) * C2);
            float ssum = 0.f;
#pragma unroll
            for (int r = 0; r < 16; ++r) {
                float e = exp2f((p[r] - mnew) * C2);
                p[r] = e;
                ssum += e;
            }
            ssum += __shfl_xor(ssum, 32);
            l_run = l_run * alpha + ssum;
            m_run = mnew;
#pragma unroll
            for (int dt = 0; dt < 4; ++dt) acc[dt] = acc[dt] * alpha;

            // P^T -> MFMA B-operand frags via one cross-half exchange
            u32 wb[8], sw[8];
#pragma unroll
            for (int j = 0; j < 8; ++j) wb[j] = pack_bf2(p[2 * j], p[2 * j + 1]);
#pragma unroll
            for (int j = 0; j < 8; ++j) sw[j] = __shfl_xor(wb[j], 32);
            const bool lo = (lane < 32);
            Frag4 p0, p1;
            p0.u[0] = lo ? wb[0] : sw[2];
            p0.u[1] = lo ? wb[1] : sw[3];
            p0.u[2] = lo ? sw[0] : wb[2];
            p0.u[3] = lo ? sw[1] : wb[3];
            p1.u[0] = lo ? wb[4] : sw[6];
            p1.u[1] = lo ? wb[5] : sw[7];
            p1.u[2] = lo ? sw[4] : wb[6];
            p1.u[3] = lo ? sw[5] : wb[7];

            // O^T += V^T * P^T ; V^T A-frag read per d column (2-way bank, free)
#pragma unroll
            for (int dt = 0; dt < 4; ++dt) {
                bf16x8 v0, v1;
#pragma unroll
                for (int j = 0; j < 8; ++j) {
                    v0[j] = (short)lV[(g * 8 + j) * 128 + dt * 32 + (lane & 31)];
                    v1[j] = (short)lV[(16 + g * 8 + j) * 128 + dt * 32 + (lane & 31)];
                }
                acc[dt] = __builtin_amdgcn_mfma_f32_32x32x16_bf16(v0, p0.v, acc[dt], 0, 0, 0);
                acc[dt] = __builtin_amdgcn_mfma_f32_32x32x16_bf16(v1, p1.v, acc[dt], 0, 0, 0);
            }
        }
    }

    const float inv_l = 1.0f / l_run;
    u16* orow = obuf + (rowbase + q) * 2048 + h * 128;
#pragma unroll
    for (int dt = 0; dt < 4; ++dt) {
#pragma unroll
        for (int rr = 0; rr < 4; ++rr) {
            int d0 = dt * 32 + rr * 8 + g * 4;   // d' = (r&3)+8*(r>>2)+4g+32dt
            int r0 = rr * 4;
            u32 w0 = pack_bf2(acc[dt][r0] * inv_l,     acc[dt][r0 + 1] * inv_l);
            u32 w1 = pack_bf2(acc[dt][r0 + 2] * inv_l, acc[dt][r0 + 3] * inv_l);
            *(u32*)(orow + d0)     = w0;
            *(u32*)(orow + d0 + 2) = w1;
        }
    }
}

extern "C" void kernel_launch(void* const* d_in, const int* in_sizes, int n_in,
                              void* d_out, int out_size, void* d_ws, size_t ws_size,
                              hipStream_t stream) {
    (void)in_sizes; (void)n_in; (void)out_size; (void)ws_size;
    const float* x    = (const float*)d_in[0];
    const float* Wqkv = (const float*)d_in[1];
    const float* bqkv = (const float*)d_in[2];
    const float* Wout = (const float*)d_in[3];
    const float* bout = (const float*)d_in[4];

    char* ws = (char*)d_ws;
    u16* xb  = (u16*)ws;                        // [4096,2048] bf16, 16 MB
    u16* wqb = (u16*)(ws + (size_t)16777216);   // [6144,2048] bf16, 24 MB
    u16* qkv = (u16*)(ws + (size_t)41943040);   // [4096,6144] bf16, 48 MB
    u16* ob  = xb;   // attention out reuses xb (x dead after GEMM1)
    u16* wob = wqb;  // W_out bf16 reuses wqb (dead after GEMM1)

    cvt_f32_bf16<<<2048, 256, 0, stream>>>(x, xb, 8388608L / 8);
    cvt_f32_bf16<<<2048, 256, 0, stream>>>(Wqkv, wqb, 12582912L / 8);
    gemm_nt<1><<<dim3(32, 48), 256, 0, stream>>>(xb, wqb, bqkv, qkv, 2048, 6144);
    attn_fwd<<<512, 256, 0, stream>>>(qkv, ob);
    cvt_f32_bf16<<<2048, 256, 0, stream>>>(Wout, wob, 4194304L / 8);
    gemm_nt<0><<<dim3(32, 16), 256, 0, stream>>>(ob, wob, bout, d_out, 2048, 2048);
}

// Round 2
// 413.555 us; speedup vs baseline: 1.8972x; 1.8972x over previous
//
#include <hip/hip_runtime.h>
#include <stdint.h>

typedef short bf16x8 __attribute__((ext_vector_type(8)));
typedef float f32x4 __attribute__((ext_vector_type(4)));
typedef float f32x16 __attribute__((ext_vector_type(16)));
typedef unsigned short u16;
typedef unsigned int u32;

__device__ __forceinline__ u16 f2bf(float f) {
    u32 x = __float_as_uint(f);
    x += 0x7fffu + ((x >> 16) & 1u);
    return (u16)(x >> 16);
}
__device__ __forceinline__ u32 pack_bf2(float a, float b) {
    return (u32)f2bf(a) | ((u32)f2bf(b) << 16);
}

union Frag4 { u32 u[4]; bf16x8 v; };

// async global->LDS, 16B per lane; LDS dest is wave-uniform base + lane*16
__device__ __forceinline__ void gload16(const u16* g, u16* l) {
    __builtin_amdgcn_global_load_lds(
        (__attribute__((address_space(1))) void*)g,
        (__attribute__((address_space(3))) void*)l,
        16, 0, 0);
}

// ---------------- f32 -> bf16 cast, 8 elems/thread (G13: vectorized) --------
__global__ void cvt_f32_bf16(const float* __restrict__ in, u16* __restrict__ out, long n8) {
    long stride = (long)gridDim.x * blockDim.x;
    for (long i = (long)blockIdx.x * blockDim.x + threadIdx.x; i < n8; i += stride) {
        const float4* p = (const float4*)(in + i * 8);
        float4 a = p[0], b = p[1];
        uint4 o;
        o.x = pack_bf2(a.x, a.y);
        o.y = pack_bf2(a.z, a.w);
        o.z = pack_bf2(b.x, b.y);
        o.w = pack_bf2(b.z, b.w);
        ((uint4*)out)[i] = o;
    }
}

// ---------------- bf16 NT GEMM: out = A * B^T + bias ------------------------
// m97 structure: 128x128 tile, BK=64, 4 waves (2x2 of 64x64), linear LDS,
// global_load_lds width=16 staging, 2-barrier K-loop, XCD-swizzled block id.
// A [M,K] bf16 row-major, B [N,K] bf16 row-major.
template<int OBF>
__global__ __launch_bounds__(256) void gemm_nt(
    const u16* __restrict__ A, const u16* __restrict__ B,
    const float* __restrict__ bias, void* __restrict__ out,
    int K, int ldo, int gxsh)
{
    __shared__ __align__(16) u16 lA[128 * 64];
    __shared__ __align__(16) u16 lB[128 * 64];
    const int tid  = threadIdx.x;
    const int lane = tid & 63;
    const int w    = tid >> 6;
    const int wm = (w >> 1) * 64, wn = (w & 1) * 64;

    // XCD-aware bijective swizzle (nwg % 8 == 0 for both call sites)
    const int nwg = gridDim.x;
    const int bid = blockIdx.x;
    const int swz = (bid & 7) * (nwg >> 3) + (bid >> 3);
    const int bm = (swz & ((1 << gxsh) - 1)) * 128;
    const int bn = (swz >> gxsh) * 128;

    // staging geometry: chunk c (0..15) = 1KB = 8 rows x 64 cols bf16
    const int lr = lane >> 3;        // row within chunk
    const int lc = (lane & 7) * 8;   // col (elems) within row

    f32x4 acc[4][4];
#pragma unroll
    for (int i = 0; i < 4; ++i)
#pragma unroll
        for (int j = 0; j < 4; ++j)
#pragma unroll
            for (int r = 0; r < 4; ++r) acc[i][j][r] = 0.f;

    for (int k0 = 0; k0 < K; k0 += 64) {
#pragma unroll
        for (int i = 0; i < 4; ++i) {
            const int c = w * 4 + i;               // wave-uniform chunk id
            const int row = c * 8 + lr;
            gload16(A + (size_t)(bm + row) * K + k0 + lc, lA + c * 512);
            gload16(B + (size_t)(bn + row) * K + k0 + lc, lB + c * 512);
        }
        __syncthreads();   // compiler emits vmcnt(0) drain here (known cost)
#pragma unroll
        for (int kk = 0; kk < 2; ++kk) {
            bf16x8 af[4], bfr[4];
#pragma unroll
            for (int f = 0; f < 4; ++f) {
                const int m = wm + f * 16 + (lane & 15);
                af[f]  = *(const bf16x8*)(lA + m * 64 + kk * 32 + (lane >> 4) * 8);
                const int n = wn + f * 16 + (lane & 15);
                bfr[f] = *(const bf16x8*)(lB + n * 64 + kk * 32 + (lane >> 4) * 8);
            }
#pragma unroll
            for (int i = 0; i < 4; ++i)
#pragma unroll
                for (int j = 0; j < 4; ++j)
                    acc[i][j] = __builtin_amdgcn_mfma_f32_16x16x32_bf16(af[i], bfr[j], acc[i][j], 0, 0, 0);
        }
        __syncthreads();   // reads done before next stage overwrites LDS
    }
    // epilogue: C/D layout col=lane&15, row=(lane>>4)*4+reg (m89-verified)
#pragma unroll
    for (int i = 0; i < 4; ++i) {
        int m0 = bm + wm + i * 16 + ((lane >> 4) << 2);
#pragma unroll
        for (int j = 0; j < 4; ++j) {
            int n = bn + wn + j * 16 + (lane & 15);
            float bv = bias[n];
#pragma unroll
            for (int r = 0; r < 4; ++r) {
                float v = acc[i][j][r] + bv;
                if constexpr (OBF != 0)
                    ((u16*)out)[(size_t)(m0 + r) * ldo + n] = f2bf(v);
                else
                    ((float*)out)[(size_t)(m0 + r) * ldo + n] = v;
            }
        }
    }
}

// ---------------- causal flash attention ------------------------------------
// qkv [B*T, 6144] bf16 (cols: Q 0..2047, K 2048..4095, V 4096..6143; head h at
// h*128). One block = (b, h, 128 q rows); 4 waves x 32 q rows each; KVBLK=32.
// Swapped QK^T: S^T = mfma32(K,Q) so lane owns q = lane&31's softmax state.
// Swapped PV: O^T = mfma32(V^T, P^T) so online rescale is lane-uniform.
__global__ __launch_bounds__(256) void attn_fwd(
    const u16* __restrict__ qkv, u16* __restrict__ obuf)
{
    __shared__ u16 lK[32 * 128];  // swizzled rows (256B)
    __shared__ u16 lV[32 * 128];  // linear
    const int tid  = threadIdx.x;
    const int lane = tid & 63;
    const int w    = tid >> 6;
    const int g    = lane >> 5;

    // load-balance: pair short (qt) with long (15-qt) tiles across the grid
    int qi = blockIdx.x >> 5;
    int bh = blockIdx.x & 31;
    int qt = (qi < 8) ? qi : 23 - qi;
    int b = bh >> 4, h = bh & 15;
    const size_t rowbase = (size_t)b * 2048;
    const int qb = qt * 128;
    const int qw = qb + w * 32;
    const int q  = qw + (lane & 31);

    // Q as MFMA B-operand frags: qf[ch][j] = Q[q][ch*16 + g*8 + j]
    bf16x8 qf[8];
    {
        const u16* qrow = qkv + (rowbase + q) * 6144 + h * 128;
#pragma unroll
        for (int ch = 0; ch < 8; ++ch)
            qf[ch] = *(const bf16x8*)(qrow + ch * 16 + g * 8);
    }

    f32x16 acc[4];
#pragma unroll
    for (int dt = 0; dt < 4; ++dt)
#pragma unroll
        for (int r = 0; r < 16; ++r) acc[dt][r] = 0.f;

    float m_run = -1e30f, l_run = 0.f;
    const float C2 = 0.08838834764831845f * 1.44269504088896341f; // scale*log2e
    const int nt = qb / 32 + 4;

    for (int t = 0; t < nt; ++t) {
        const int kb = t * 32;
        uint4 rk[2], rv[2];
#pragma unroll
        for (int i = 0; i < 2; ++i) {
            u32 o = i * 4096 + tid * 16;
            u32 r = o >> 8, c = (o & 255) >> 1;
            const u16* src = qkv + (rowbase + kb + r) * 6144 + h * 128 + c;
            rk[i] = *(const uint4*)(src + 2048);
            rv[i] = *(const uint4*)(src + 4096);
        }
        __syncthreads();
#pragma unroll
        for (int i = 0; i < 2; ++i) {
            u32 o = i * 4096 + tid * 16;
            u32 r = o >> 8, byt = o & 255;
            *(uint4*)((char*)lK + r * 256 + (byt ^ ((r & 15) << 4))) = rk[i];
            *(uint4*)((char*)lV + o) = rv[i];
        }
        __syncthreads();

        if (kb <= qw + 31) {
            // S^T tile [32k x 32q]; 8 d-chunks of 16
            f32x16 s;
#pragma unroll
            for (int r = 0; r < 16; ++r) s[r] = 0.f;
            __builtin_amdgcn_s_setprio(1);
#pragma unroll
            for (int ch = 0; ch < 8; ++ch) {
                u32 r = lane & 31;
                u32 byt = (u32)(ch * 32 + g * 16);
                bf16x8 kf = *(const bf16x8*)((const char*)lK + r * 256 + (byt ^ ((r & 15) << 4)));
                s = __builtin_amdgcn_mfma_f32_32x32x16_bf16(kf, qf[ch], s, 0, 0, 0);
            }
            __builtin_amdgcn_s_setprio(0);
            // lane holds S^T[k'][q=lane&31], k'(r) = (r&3)+8*(r>>2)+4*g
            float p[16];
            float tmax = -1e30f;
#pragma unroll
            for (int r = 0; r < 16; ++r) {
                int kg = kb + (r & 3) + 8 * (r >> 2) + 4 * g;
                float v = s[r];
                if (kg > q) v = -1e30f;     // causal mask
                p[r] = v;
                tmax = fmaxf(tmax, v);
            }
            tmax = fmaxf(tmax, __shfl_xor(tmax, 32)); // other k-half
            float mnew  = fmaxf(m_run, tmax);
            float alpha = exp2f((m_run - mnew) * C2);
            float ssum = 0.f;
#pragma unroll
            for (int r = 0; r < 16; ++r) {
                float e = exp2f((p[r] - mnew) * C2);
                p[r] = e;
                ssum += e;
            }
            ssum += __shfl_xor(ssum, 32);
            l_run = l_run * alpha + ssum;
            m_run = mnew;
#pragma unroll
            for (int dt = 0; dt < 4; ++dt) acc[dt] = acc[dt] * alpha;

            // P^T -> MFMA B-operand frags via one cross-half exchange
            u32 wb[8], sw[8];
#pragma unroll
            for (int j = 0; j < 8; ++j) wb[j] = pack_bf2(p[2 * j], p[2 * j + 1]);
#pragma unroll
            for (int j = 0; j < 8; ++j) sw[j] = __shfl_xor(wb[j], 32);
            const bool lo = (lane < 32);
            Frag4 p0, p1;
            p0.u[0] = lo ? wb[0] : sw[2];
            p0.u[1] = lo ? wb[1] : sw[3];
            p0.u[2] = lo ? sw[0] : wb[2];
            p0.u[3] = lo ? sw[1] : wb[3];
            p1.u[0] = lo ? wb[4] : sw[6];
            p1.u[1] = lo ? wb[5] : sw[7];
            p1.u[2] = lo ? sw[4] : wb[6];
            p1.u[3] = lo ? sw[5] : wb[7];

            // O^T += V^T * P^T ; V^T A-frag read per d column (2-way bank, free)
#pragma unroll
            for (int dt = 0; dt < 4; ++dt) {
                bf16x8 v0, v1;
#pragma unroll
                for (int j = 0; j < 8; ++j) {
                    v0[j] = (short)lV[(g * 8 + j) * 128 + dt * 32 + (lane & 31)];
                    v1[j] = (short)lV[(16 + g * 8 + j) * 128 + dt * 32 + (lane & 31)];
                }
                __builtin_amdgcn_s_setprio(1);
                acc[dt] = __builtin_amdgcn_mfma_f32_32x32x16_bf16(v0, p0.v, acc[dt], 0, 0, 0);
                acc[dt] = __builtin_amdgcn_mfma_f32_32x32x16_bf16(v1, p1.v, acc[dt], 0, 0, 0);
                __builtin_amdgcn_s_setprio(0);
            }
        }
    }

    const float inv_l = 1.0f / l_run;
    u16* orow = obuf + (rowbase + q) * 2048 + h * 128;
#pragma unroll
    for (int dt = 0; dt < 4; ++dt) {
#pragma unroll
        for (int rr = 0; rr < 4; ++rr) {
            int d0 = dt * 32 + rr * 8 + g * 4;   // d' = (r&3)+8*(r>>2)+4g+32dt
            int r0 = rr * 4;
            u32 w0 = pack_bf2(acc[dt][r0] * inv_l,     acc[dt][r0 + 1] * inv_l);
            u32 w1 = pack_bf2(acc[dt][r0 + 2] * inv_l, acc[dt][r0 + 3] * inv_l);
            *(u32*)(orow + d0)     = w0;
            *(u32*)(orow + d0 + 2) = w1;
        }
    }
}

extern "C" void kernel_launch(void* const* d_in, const int* in_sizes, int n_in,
                              void* d_out, int out_size, void* d_ws, size_t ws_size,
                              hipStream_t stream) {
    (void)in_sizes; (void)n_in; (void)out_size; (void)ws_size;
    const float* x    = (const float*)d_in[0];
    const float* Wqkv = (const float*)d_in[1];
    const float* bqkv = (const float*)d_in[2];
    const float* Wout = (const float*)d_in[3];
    const float* bout = (const float*)d_in[4];

    char* ws = (char*)d_ws;
    u16* xb  = (u16*)ws;                        // [4096,2048] bf16, 16 MB
    u16* wqb = (u16*)(ws + (size_t)16777216);   // [6144,2048] bf16, 24 MB
    u16* qkv = (u16*)(ws + (size_t)41943040);   // [4096,6144] bf16, 48 MB
    u16* ob  = xb;   // attention out reuses xb (x dead after GEMM1)
    u16* wob = wqb;  // W_out bf16 reuses wqb (dead after GEMM1)

    cvt_f32_bf16<<<2048, 256, 0, stream>>>(x, xb, 8388608L / 8);
    cvt_f32_bf16<<<2048, 256, 0, stream>>>(Wqkv, wqb, 12582912L / 8);
    // M-tiles = 32 (gxsh=5): QKV gemm grid 32x48=1536, out gemm 32x16=512
    gemm_nt<1><<<1536, 256, 0, stream>>>(xb, wqb, bqkv, qkv, 2048, 6144, 5);
    attn_fwd<<<512, 256, 0, stream>>>(qkv, ob);
    cvt_f32_bf16<<<2048, 256, 0, stream>>>(Wout, wob, 4194304L / 8);
    gemm_nt<0><<<512, 256, 0, stream>>>(ob, wob, bout, d_out, 2048, 2048, 5);
}

// Round 3
// 398.026 us; speedup vs baseline: 1.9713x; 1.0390x over previous
//
#include <hip/hip_runtime.h>
#include <stdint.h>

typedef short bf16x8 __attribute__((ext_vector_type(8)));
typedef float f32x4 __attribute__((ext_vector_type(4)));
typedef float f32x16 __attribute__((ext_vector_type(16)));
typedef unsigned short u16;
typedef unsigned int u32;

__device__ __forceinline__ u16 f2bf(float f) {
    u32 x = __float_as_uint(f);
    x += 0x7fffu + ((x >> 16) & 1u);
    return (u16)(x >> 16);
}
__device__ __forceinline__ u32 pack_bf2(float a, float b) {
    return (u32)f2bf(a) | ((u32)f2bf(b) << 16);
}

union Frag4 { u32 u[4]; bf16x8 v; };

// async global->LDS, 16B per lane; LDS dest is wave-uniform base + lane*16
__device__ __forceinline__ void gload16(const u16* g, u16* l) {
    __builtin_amdgcn_global_load_lds(
        (__attribute__((address_space(1))) void*)g,
        (__attribute__((address_space(3))) void*)l,
        16, 0, 0);
}

// ---------------- f32 -> bf16 cast, 8 elems/thread (G13: vectorized) --------
__global__ void cvt_f32_bf16(const float* __restrict__ in, u16* __restrict__ out, long n8) {
    long stride = (long)gridDim.x * blockDim.x;
    for (long i = (long)blockIdx.x * blockDim.x + threadIdx.x; i < n8; i += stride) {
        const float4* p = (const float4*)(in + i * 8);
        float4 a = p[0], b = p[1];
        uint4 o;
        o.x = pack_bf2(a.x, a.y);
        o.y = pack_bf2(a.z, a.w);
        o.z = pack_bf2(b.x, b.y);
        o.w = pack_bf2(b.z, b.w);
        ((uint4*)out)[i] = o;
    }
}

// ---------------- bf16 NT GEMM: out = A * B^T + bias ------------------------
// m97 structure: 128x128 tile, BK=64, 4 waves (2x2 of 64x64), linear LDS,
// global_load_lds width=16 staging, 2-barrier K-loop, XCD-swizzled block id.
template<int OBF>
__global__ __launch_bounds__(256) void gemm_nt(
    const u16* __restrict__ A, const u16* __restrict__ B,
    const float* __restrict__ bias, void* __restrict__ out,
    int K, int ldo, int gxsh)
{
    __shared__ __align__(16) u16 lA[128 * 64];
    __shared__ __align__(16) u16 lB[128 * 64];
    const int tid  = threadIdx.x;
    const int lane = tid & 63;
    const int w    = tid >> 6;
    const int wm = (w >> 1) * 64, wn = (w & 1) * 64;

    // XCD-aware bijective swizzle (nwg % 8 == 0 for both call sites)
    const int nwg = gridDim.x;
    const int bid = blockIdx.x;
    const int swz = (bid & 7) * (nwg >> 3) + (bid >> 3);
    const int bm = (swz & ((1 << gxsh) - 1)) * 128;
    const int bn = (swz >> gxsh) * 128;

    // staging geometry: chunk c (0..15) = 1KB = 8 rows x 64 cols bf16
    const int lr = lane >> 3;        // row within chunk
    const int lc = (lane & 7) * 8;   // col (elems) within row

    f32x4 acc[4][4];
#pragma unroll
    for (int i = 0; i < 4; ++i)
#pragma unroll
        for (int j = 0; j < 4; ++j)
#pragma unroll
            for (int r = 0; r < 4; ++r) acc[i][j][r] = 0.f;

    for (int k0 = 0; k0 < K; k0 += 64) {
#pragma unroll
        for (int i = 0; i < 4; ++i) {
            const int c = w * 4 + i;               // wave-uniform chunk id
            const int row = c * 8 + lr;
            gload16(A + (size_t)(bm + row) * K + k0 + lc, lA + c * 512);
            gload16(B + (size_t)(bn + row) * K + k0 + lc, lB + c * 512);
        }
        __syncthreads();
#pragma unroll
        for (int kk = 0; kk < 2; ++kk) {
            bf16x8 af[4], bfr[4];
#pragma unroll
            for (int f = 0; f < 4; ++f) {
                const int m = wm + f * 16 + (lane & 15);
                af[f]  = *(const bf16x8*)(lA + m * 64 + kk * 32 + (lane >> 4) * 8);
                const int n = wn + f * 16 + (lane & 15);
                bfr[f] = *(const bf16x8*)(lB + n * 64 + kk * 32 + (lane >> 4) * 8);
            }
#pragma unroll
            for (int i = 0; i < 4; ++i)
#pragma unroll
                for (int j = 0; j < 4; ++j)
                    acc[i][j] = __builtin_amdgcn_mfma_f32_16x16x32_bf16(af[i], bfr[j], acc[i][j], 0, 0, 0);
        }
        __syncthreads();
    }
#pragma unroll
    for (int i = 0; i < 4; ++i) {
        int m0 = bm + wm + i * 16 + ((lane >> 4) << 2);
#pragma unroll
        for (int j = 0; j < 4; ++j) {
            int n = bn + wn + j * 16 + (lane & 15);
            float bv = bias[n];
#pragma unroll
            for (int r = 0; r < 4; ++r) {
                float v = acc[i][j][r] + bv;
                if constexpr (OBF != 0)
                    ((u16*)out)[(size_t)(m0 + r) * ldo + n] = f2bf(v);
                else
                    ((float*)out)[(size_t)(m0 + r) * ldo + n] = v;
            }
        }
    }
}

// ---------------- V transpose: vt[b,h,d,t] <- qkv[b*2048+t][4096+h*128+d] ---
// 64t x 64d tiles via XOR-swizzled LDS; coalesced uint4 in and out.
__global__ __launch_bounds__(256) void transpose_v(
    const u16* __restrict__ qkv, u16* __restrict__ vt)
{
    __shared__ u16 lt[64 * 64];   // rows of 128B, slot XOR-swizzled
    const int tid = threadIdx.x;
    const int bid = blockIdx.x;
    const int tt    = bid & 31;
    const int dtile = (bid >> 5) & 1;
    const int h     = (bid >> 6) & 15;
    const int b     = bid >> 10;
    const u16* src = qkv + ((size_t)b * 2048 + tt * 64) * 6144 + 4096 + h * 128 + dtile * 64;

    const int r = tid >> 2, ce = (tid & 3) * 16;   // row t, elem col in tile
    uint4 a0 = *(const uint4*)(src + (size_t)r * 6144 + ce);
    uint4 a1 = *(const uint4*)(src + (size_t)r * 6144 + ce + 8);
    const u32 swz = (u32)((r & 7) << 4);
    *(uint4*)((char*)lt + r * 128 + (((u32)(ce * 2)) ^ swz)) = a0;
    *(uint4*)((char*)lt + r * 128 + (((u32)(ce * 2 + 16)) ^ swz)) = a1;
    __syncthreads();

    const int d = tid >> 2;
    u16* dst = vt + ((size_t)(b * 16 + h) * 128 + dtile * 64 + d) * 2048 + tt * 64;
#pragma unroll
    for (int it = 0; it < 2; ++it) {
        const int t0 = (tid & 3) * 8 + it * 32;
        union { u16 hh[8]; uint4 q4; } u;
#pragma unroll
        for (int uu = 0; uu < 8; ++uu) {
            int trow = t0 + uu;
            u32 byt = (u32)(trow * 128) + (((u32)(d * 2)) ^ ((u32)((trow & 7) << 4)));
            u.hh[uu] = *(const u16*)((const char*)lt + byt);
        }
        *(uint4*)(dst + t0) = u.q4;
    }
}

// ---------------- causal flash attention (barrier-free, LDS-free) -----------
// One wave per (b, h, 32 q rows); 2048 waves total, longest q-tile first.
// K frags read from qkv (d-contiguous), V^T frags from vt (t-contiguous);
// per-head K/V slices (512KB) are L2-resident and shared by 64 waves.
// Swapped QK^T: S^T = mfma32(K,Q) -> lane owns q = lane&31's softmax state.
// Swapped PV: O^T = mfma32(V^T, P^T) -> rescale is lane-uniform.
__global__ __launch_bounds__(256) void attn_fwd(
    const u16* __restrict__ qkv, const u16* __restrict__ vt,
    u16* __restrict__ obuf)
{
    const int tid  = threadIdx.x;
    const int lane = tid & 63;
    const int g    = lane >> 5;
    const int ql   = lane & 31;

    const int W  = blockIdx.x * 4 + (tid >> 6);   // 0..2047
    const int qi = W >> 5;
    const int bh = W & 31;
    const int qt = 63 - qi;                        // longest first
    const int b = bh >> 4, h = bh & 15;
    const size_t rowbase = (size_t)b * 2048;
    const int qw = qt * 32;
    const int q  = qw + ql;

    const u16* Kbase = qkv + rowbase * 6144 + 2048 + h * 128; // K[t][d], ld 6144
    const u16* Vth   = vt + (size_t)bh * 128 * 2048;          // Vt[d][t]

    // Q as MFMA B-operand frags: qf[ch][j] = Q[q][ch*16 + g*8 + j]
    bf16x8 qf[8];
    {
        const u16* qrow = qkv + (rowbase + q) * 6144 + h * 128;
#pragma unroll
        for (int ch = 0; ch < 8; ++ch)
            qf[ch] = *(const bf16x8*)(qrow + ch * 16 + g * 8);
    }

    f32x16 acc[4];
#pragma unroll
    for (int dt = 0; dt < 4; ++dt)
#pragma unroll
        for (int r = 0; r < 16; ++r) acc[dt][r] = 0.f;

    float m_run = -1e30f, l_run = 0.f;
    const float C2 = 0.08838834764831845f * 1.44269504088896341f; // scale*log2e
    const int nt = qt + 1;                          // KV tiles of 32

    for (int t = 0; t < nt; ++t) {
        const int kb = t * 32;
        // K fragments (A-operand): kf[ch][j] = K[kb+ql][ch*16+g*8+j]
        const u16* krow = Kbase + (size_t)(kb + ql) * 6144;
        bf16x8 kf[8];
#pragma unroll
        for (int ch = 0; ch < 8; ++ch)
            kf[ch] = *(const bf16x8*)(krow + ch * 16 + g * 8);
        // V^T fragments (A-operand), issued early; drain during softmax
        bf16x8 vf0[4], vf1[4];
#pragma unroll
        for (int dt = 0; dt < 4; ++dt) {
            const u16* vrow = Vth + (size_t)(dt * 32 + ql) * 2048 + kb + g * 8;
            vf0[dt] = *(const bf16x8*)(vrow);
            vf1[dt] = *(const bf16x8*)(vrow + 16);
        }

        f32x16 s;
#pragma unroll
        for (int r = 0; r < 16; ++r) s[r] = 0.f;
        __builtin_amdgcn_s_setprio(1);
#pragma unroll
        for (int ch = 0; ch < 8; ++ch)
            s = __builtin_amdgcn_mfma_f32_32x32x16_bf16(kf[ch], qf[ch], s, 0, 0, 0);
        __builtin_amdgcn_s_setprio(0);

        // lane holds S^T[k'][q], k'(r) = (r&3)+8*(r>>2)+4*g
        const bool last = (t == nt - 1);
        float p[16];
        float tmax = -1e30f;
#pragma unroll
        for (int r = 0; r < 16; ++r) {
            int kg = kb + (r & 3) + 8 * (r >> 2) + 4 * g;
            float v = s[r];
            if (last && (kg > q)) v = -1e30f;      // causal mask (last tile only)
            p[r] = v;
            tmax = fmaxf(tmax, v);
        }
        tmax = fmaxf(tmax, __shfl_xor(tmax, 32));
        // T13 defer-max: skip O/l rescale while max grows < 8 (exact algebra)
        if (!__all(tmax <= m_run + 8.0f)) {
            float mnew  = fmaxf(m_run, tmax);
            float alpha = exp2f((m_run - mnew) * C2);
#pragma unroll
            for (int dt = 0; dt < 4; ++dt) acc[dt] = acc[dt] * alpha;
            l_run *= alpha;
            m_run = mnew;
        }
        float ssum = 0.f;
#pragma unroll
        for (int r = 0; r < 16; ++r) {
            float e = exp2f((p[r] - m_run) * C2);
            p[r] = e;
            ssum += e;
        }
        ssum += __shfl_xor(ssum, 32);
        l_run += ssum;

        // P^T -> MFMA B-operand frags via one cross-half exchange
        u32 wb[8], sw[8];
#pragma unroll
        for (int j = 0; j < 8; ++j) wb[j] = pack_bf2(p[2 * j], p[2 * j + 1]);
#pragma unroll
        for (int j = 0; j < 8; ++j) sw[j] = __shfl_xor(wb[j], 32);
        Frag4 pf0, pf1;
#pragma unroll
        for (int u = 0; u < 4; ++u) {
            const bool own = (g == (u >> 1));
            pf0.u[u] = own ? wb[2 * g + (u & 1)]     : sw[2 * g + (u & 1)];
            pf1.u[u] = own ? wb[4 + 2 * g + (u & 1)] : sw[4 + 2 * g + (u & 1)];
        }

        __builtin_amdgcn_s_setprio(1);
#pragma unroll
        for (int dt = 0; dt < 4; ++dt)
            acc[dt] = __builtin_amdgcn_mfma_f32_32x32x16_bf16(vf0[dt], pf0.v, acc[dt], 0, 0, 0);
#pragma unroll
        for (int dt = 0; dt < 4; ++dt)
            acc[dt] = __builtin_amdgcn_mfma_f32_32x32x16_bf16(vf1[dt], pf1.v, acc[dt], 0, 0, 0);
        __builtin_amdgcn_s_setprio(0);
    }

    const float inv_l = 1.0f / l_run;
    u16* orow = obuf + (rowbase + q) * 2048 + h * 128;
#pragma unroll
    for (int dt = 0; dt < 4; ++dt) {
#pragma unroll
        for (int rr = 0; rr < 4; ++rr) {
            int d0 = dt * 32 + rr * 8 + g * 4;   // d' = (r&3)+8*(r>>2)+4g+32dt
            int r0 = rr * 4;
            u32 w0 = pack_bf2(acc[dt][r0] * inv_l,     acc[dt][r0 + 1] * inv_l);
            u32 w1 = pack_bf2(acc[dt][r0 + 2] * inv_l, acc[dt][r0 + 3] * inv_l);
            *(u32*)(orow + d0)     = w0;
            *(u32*)(orow + d0 + 2) = w1;
        }
    }
}

extern "C" void kernel_launch(void* const* d_in, const int* in_sizes, int n_in,
                              void* d_out, int out_size, void* d_ws, size_t ws_size,
                              hipStream_t stream) {
    (void)in_sizes; (void)n_in; (void)out_size; (void)ws_size;
    const float* x    = (const float*)d_in[0];
    const float* Wqkv = (const float*)d_in[1];
    const float* bqkv = (const float*)d_in[2];
    const float* Wout = (const float*)d_in[3];
    const float* bout = (const float*)d_in[4];

    char* ws = (char*)d_ws;
    u16* xb  = (u16*)ws;                        // [4096,2048] bf16, 16 MB
    u16* wqb = (u16*)(ws + (size_t)16777216);   // [6144,2048] bf16, 24 MB
    u16* qkv = (u16*)(ws + (size_t)41943040);   // [4096,6144] bf16, 48 MB
    u16* ob  = xb;   // attention out reuses xb (x dead after GEMM1)
    u16* vtb = wqb;  // V^T [32,128,2048] bf16 16 MB reuses wqb (dead after GEMM1)
    u16* wob = wqb;  // W_out bf16 reuses wqb again (vtb dead after attn)

    cvt_f32_bf16<<<2048, 256, 0, stream>>>(x, xb, 8388608L / 8);
    cvt_f32_bf16<<<2048, 256, 0, stream>>>(Wqkv, wqb, 12582912L / 8);
    gemm_nt<1><<<1536, 256, 0, stream>>>(xb, wqb, bqkv, qkv, 2048, 6144, 5);
    transpose_v<<<2048, 256, 0, stream>>>(qkv, vtb);
    attn_fwd<<<512, 256, 0, stream>>>(qkv, vtb, ob);
    cvt_f32_bf16<<<2048, 256, 0, stream>>>(Wout, wob, 4194304L / 8);
    gemm_nt<0><<<512, 256, 0, stream>>>(ob, wob, bout, d_out, 2048, 2048, 5);
}

// Round 4
// 365.603 us; speedup vs baseline: 2.1461x; 1.0887x over previous
//
#include <hip/hip_runtime.h>
#include <stdint.h>

typedef short bf16x8 __attribute__((ext_vector_type(8)));
typedef float f32x4 __attribute__((ext_vector_type(4)));
typedef float f32x16 __attribute__((ext_vector_type(16)));
typedef unsigned short u16;
typedef unsigned int u32;

__device__ __forceinline__ u16 f2bf(float f) {
    u32 x = __float_as_uint(f);
    x += 0x7fffu + ((x >> 16) & 1u);
    return (u16)(x >> 16);
}
__device__ __forceinline__ u32 pack_bf2(float a, float b) {
    return (u32)f2bf(a) | ((u32)f2bf(b) << 16);
}

union Frag4 { u32 u[4]; bf16x8 v; };

// async global->LDS, 16B per lane; LDS dest is wave-uniform base + lane*16
__device__ __forceinline__ void gload16(const u16* g, u16* l) {
    __builtin_amdgcn_global_load_lds(
        (__attribute__((address_space(1))) void*)g,
        (__attribute__((address_space(3))) void*)l,
        16, 0, 0);
}

// ---------------- f32 -> bf16 cast, 8 elems/thread (G13: vectorized) --------
__global__ void cvt_f32_bf16(const float* __restrict__ in, u16* __restrict__ out, long n8) {
    long stride = (long)gridDim.x * blockDim.x;
    for (long i = (long)blockIdx.x * blockDim.x + threadIdx.x; i < n8; i += stride) {
        const float4* p = (const float4*)(in + i * 8);
        float4 a = p[0], b = p[1];
        uint4 o;
        o.x = pack_bf2(a.x, a.y);
        o.y = pack_bf2(a.z, a.w);
        o.z = pack_bf2(b.x, b.y);
        o.w = pack_bf2(b.z, b.w);
        ((uint4*)out)[i] = o;
    }
}

// ---------------- bf16 NT GEMM: out = A * B^T + bias ------------------------
// m97 structure: 128x128 tile, BK=64, 4 waves (2x2 of 64x64),
// global_load_lds width=16 staging with pre-swizzled source (rule #21),
// XOR-swizzled ds_read_b128 (bank-floor), 2-barrier K-loop, XCD swizzle.
template<int OBF>
__global__ __launch_bounds__(256) void gemm_nt(
    const u16* __restrict__ A, const u16* __restrict__ B,
    const float* __restrict__ bias, void* __restrict__ out,
    int K, int ldo, int gxsh)
{
    __shared__ __align__(16) u16 lA[128 * 64];
    __shared__ __align__(16) u16 lB[128 * 64];
    const int tid  = threadIdx.x;
    const int lane = tid & 63;
    const int w    = tid >> 6;
    const int wm = (w >> 1) * 64, wn = (w & 1) * 64;

    // XCD-aware bijective swizzle (nwg % 8 == 0 for both call sites)
    const int nwg = gridDim.x;
    const int bid = blockIdx.x;
    const int swz = (bid & 7) * (nwg >> 3) + (bid >> 3);
    const int bm = (swz & ((1 << gxsh) - 1)) * 128;
    const int bn = (swz >> gxsh) * 128;

    // staging: chunk c (0..15) = 1KB = 8 rows x 128B; involution-swizzled src
    const int lr = lane >> 3;                       // row within chunk
    const u32 sb = (u32)((lane & 7) * 16);          // stored byte-in-row

    f32x4 acc[4][4];
#pragma unroll
    for (int i = 0; i < 4; ++i)
#pragma unroll
        for (int j = 0; j < 4; ++j)
#pragma unroll
            for (int r = 0; r < 4; ++r) acc[i][j][r] = 0.f;

    for (int k0 = 0; k0 < K; k0 += 64) {
#pragma unroll
        for (int i = 0; i < 4; ++i) {
            const int c = w * 4 + i;               // wave-uniform chunk id
            const int row = c * 8 + lr;
            const u32 col = (sb ^ ((u32)(row & 7) << 4)) >> 1;   // elems
            gload16(A + (size_t)(bm + row) * K + k0 + col, lA + c * 512);
            gload16(B + (size_t)(bn + row) * K + k0 + col, lB + c * 512);
        }
        __syncthreads();
#pragma unroll
        for (int kk = 0; kk < 2; ++kk) {
            bf16x8 af[4], bfr[4];
#pragma unroll
            for (int f = 0; f < 4; ++f) {
                const int m = wm + f * 16 + (lane & 15);
                const u32 byt = (u32)(kk * 64 + (lane >> 4) * 16) ^ ((u32)(m & 7) << 4);
                af[f]  = *(const bf16x8*)((const char*)lA + m * 128 + byt);
                const int n = wn + f * 16 + (lane & 15);
                const u32 bytb = (u32)(kk * 64 + (lane >> 4) * 16) ^ ((u32)(n & 7) << 4);
                bfr[f] = *(const bf16x8*)((const char*)lB + n * 128 + bytb);
            }
#pragma unroll
            for (int i = 0; i < 4; ++i)
#pragma unroll
                for (int j = 0; j < 4; ++j)
                    acc[i][j] = __builtin_amdgcn_mfma_f32_16x16x32_bf16(af[i], bfr[j], acc[i][j], 0, 0, 0);
        }
        __syncthreads();
    }
#pragma unroll
    for (int i = 0; i < 4; ++i) {
        int m0 = bm + wm + i * 16 + ((lane >> 4) << 2);
#pragma unroll
        for (int j = 0; j < 4; ++j) {
            int n = bn + wn + j * 16 + (lane & 15);
            float bv = bias[n];
#pragma unroll
            for (int r = 0; r < 4; ++r) {
                float v = acc[i][j][r] + bv;
                if constexpr (OBF != 0)
                    ((u16*)out)[(size_t)(m0 + r) * ldo + n] = f2bf(v);
                else
                    ((float*)out)[(size_t)(m0 + r) * ldo + n] = v;
            }
        }
    }
}

// ---------------- V transpose: vt[b,h,d,t] <- qkv[b*2048+t][4096+h*128+d] ---
__global__ __launch_bounds__(256) void transpose_v(
    const u16* __restrict__ qkv, u16* __restrict__ vt)
{
    __shared__ u16 lt[64 * 64];   // rows of 128B, slot XOR-swizzled
    const int tid = threadIdx.x;
    const int bid = blockIdx.x;
    const int tt    = bid & 31;
    const int dtile = (bid >> 5) & 1;
    const int h     = (bid >> 6) & 15;
    const int b     = bid >> 10;
    const u16* src = qkv + ((size_t)b * 2048 + tt * 64) * 6144 + 4096 + h * 128 + dtile * 64;

    const int r = tid >> 2, ce = (tid & 3) * 16;   // row t, elem col in tile
    uint4 a0 = *(const uint4*)(src + (size_t)r * 6144 + ce);
    uint4 a1 = *(const uint4*)(src + (size_t)r * 6144 + ce + 8);
    const u32 swz = (u32)((r & 7) << 4);
    *(uint4*)((char*)lt + r * 128 + (((u32)(ce * 2)) ^ swz)) = a0;
    *(uint4*)((char*)lt + r * 128 + (((u32)(ce * 2 + 16)) ^ swz)) = a1;
    __syncthreads();

    const int d = tid >> 2;
    u16* dst = vt + ((size_t)(b * 16 + h) * 128 + dtile * 64 + d) * 2048 + tt * 64;
#pragma unroll
    for (int it = 0; it < 2; ++it) {
        const int t0 = (tid & 3) * 8 + it * 32;
        union { u16 hh[8]; uint4 q4; } u;
#pragma unroll
        for (int uu = 0; uu < 8; ++uu) {
            int trow = t0 + uu;
            u32 byt = (u32)(trow * 128) + (((u32)(d * 2)) ^ ((u32)((trow & 7) << 4)));
            u.hh[uu] = *(const u16*)((const char*)lt + byt);
        }
        *(uint4*)(dst + t0) = u.q4;
    }
}

// ---------------- causal flash attention (m214-style, LDS-staged) -----------
// Block = (b, h, 128 q rows); 4 waves x 32 q rows. KVBLK=64, double-buffered
// LDS: K [64][128] + Vt [128][64] per buffer (64KB total), staged coalesced
// via global_load_lds with involution-swizzled source; ds_read_b128 reads
// at bank floor. One barrier per KV tile (T3-minimum pipeline).
// Swapped QK^T: S^T = mfma32(K,Q); swapped PV: O^T = mfma32(V^T, P^T).
__global__ __launch_bounds__(256) void attn_fwd(
    const u16* __restrict__ qkv, const u16* __restrict__ vt,
    u16* __restrict__ obuf)
{
    __shared__ __align__(16) u16 lK[2 * 64 * 128];
    __shared__ __align__(16) u16 lV[2 * 128 * 64];
    const int tid  = threadIdx.x;
    const int lane = tid & 63;
    const int w    = tid >> 6;
    const int g    = lane >> 5;
    const int ql   = lane & 31;

    const int bid = blockIdx.x;
    const int qi  = bid >> 5;
    const int bh  = bid & 31;
    const int qtile = (qi < 8) ? (15 - qi) : (qi - 8);  // pair long+short
    const int b = bh >> 4, h = bh & 15;
    const size_t rowbase = (size_t)b * 2048;
    const int qb = qtile * 128;
    const int qw = qb + w * 32;
    const int q  = qw + ql;
    const int nt = 2 * qtile + 2;                  // KV tiles of 64

    const u16* Khead = qkv + rowbase * 6144 + 2048 + h * 128;  // ld 6144
    const u16* Vth   = vt + (size_t)bh * 128 * 2048;           // Vt[d][t]

    // Q as MFMA B-operand frags: qf[ch][j] = Q[q][ch*16 + g*8 + j]
    bf16x8 qf[8];
    {
        const u16* qrow = qkv + (rowbase + q) * 6144 + h * 128;
#pragma unroll
        for (int ch = 0; ch < 8; ++ch)
            qf[ch] = *(const bf16x8*)(qrow + ch * 16 + g * 8);
    }

    f32x16 acc[4];
#pragma unroll
    for (int dt = 0; dt < 4; ++dt)
#pragma unroll
        for (int r = 0; r < 16; ++r) acc[dt][r] = 0.f;

    float m_run = -1e30f, l_run = 0.f;
    const float C2 = 0.08838834764831845f * 1.44269504088896341f; // scale*log2e

    // stage KV tile t into buffer bb (4 waves x (4 K + 4 V) chunks of 1KB)
    auto stage = [&](int bb, int t) {
        const int kb = t * 64;
#pragma unroll
        for (int i = 0; i < 4; ++i) {
            const int c = w * 4 + i;
            // K: chunk = 4 rows x 256B
            const int kr = c * 4 + (lane >> 4);
            const u32 kcol = (((u32)((lane & 15) * 16)) ^ ((u32)(kr & 7) << 4)) >> 1;
            gload16(Khead + (size_t)(kb + kr) * 6144 + kcol,
                    lK + bb * 8192 + c * 512);
            // Vt: chunk = 8 rows x 128B
            const int vr = c * 8 + (lane >> 3);
            const u32 vcol = (((u32)((lane & 7) * 16)) ^ ((u32)(vr & 7) << 4)) >> 1;
            gload16(Vth + (size_t)vr * 2048 + kb + vcol,
                    lV + bb * 8192 + c * 512);
        }
    };

    stage(0, 0);
    __syncthreads();
    int buf = 0;

    for (int t = 0; t < nt; ++t) {
        const int kb = t * 64;
        if (t + 1 < nt) stage(buf ^ 1, t + 1);

        if (kb <= qw + 31) {
            const char* lKb = (const char*)(lK + buf * 8192);
            const char* lVb = (const char*)(lV + buf * 8192);
#pragma unroll
            for (int s = 0; s < 2; ++s) {
                const int kb2 = kb + s * 32;
                if (kb2 > qw + 31) break;          // wave-uniform
                const bool diag = (kb2 == qw);

                // K frags from LDS (swizzled)
                bf16x8 kf[8];
                const u32 krow = (u32)(s * 32 + ql);
                const u32 ksw = (krow & 7) << 4;
#pragma unroll
                for (int ch = 0; ch < 8; ++ch)
                    kf[ch] = *(const bf16x8*)(lKb + krow * 256 + (((u32)(ch * 32 + g * 16)) ^ ksw));

                f32x16 s_;
#pragma unroll
                for (int r = 0; r < 16; ++r) s_[r] = 0.f;
                __builtin_amdgcn_s_setprio(1);
#pragma unroll
                for (int ch = 0; ch < 8; ++ch)
                    s_ = __builtin_amdgcn_mfma_f32_32x32x16_bf16(kf[ch], qf[ch], s_, 0, 0, 0);
                __builtin_amdgcn_s_setprio(0);

                // lane holds S^T[k'][q], k'(r) = (r&3)+8*(r>>2)+4*g
                float p[16];
                float tmax = -1e30f;
#pragma unroll
                for (int r = 0; r < 16; ++r) {
                    int crow = (r & 3) + 8 * (r >> 2) + 4 * g;
                    float v = s_[r];
                    if (diag && (crow > ql)) v = -1e30f;   // causal mask
                    p[r] = v;
                    tmax = fmaxf(tmax, v);
                }
                tmax = fmaxf(tmax, __shfl_xor(tmax, 32));
                // T13 defer-max: skip O/l rescale while max grows < 8
                if (!__all(tmax <= m_run + 8.0f)) {
                    float mnew  = fmaxf(m_run, tmax);
                    float alpha = exp2f((m_run - mnew) * C2);
#pragma unroll
                    for (int dt = 0; dt < 4; ++dt) acc[dt] = acc[dt] * alpha;
                    l_run *= alpha;
                    m_run = mnew;
                }
                float ssum = 0.f;
#pragma unroll
                for (int r = 0; r < 16; ++r) {
                    float e = exp2f((p[r] - m_run) * C2);
                    p[r] = e;
                    ssum += e;
                }
                ssum += __shfl_xor(ssum, 32);
                l_run += ssum;

                // P^T -> MFMA B-operand frags via one cross-half exchange
                u32 wb[8], sw[8];
#pragma unroll
                for (int j = 0; j < 8; ++j) wb[j] = pack_bf2(p[2 * j], p[2 * j + 1]);
#pragma unroll
                for (int j = 0; j < 8; ++j) sw[j] = __shfl_xor(wb[j], 32);
                Frag4 pf0, pf1;
#pragma unroll
                for (int u = 0; u < 4; ++u) {
                    const bool own = (g == (u >> 1));
                    pf0.u[u] = own ? wb[2 * g + (u & 1)]     : sw[2 * g + (u & 1)];
                    pf1.u[u] = own ? wb[4 + 2 * g + (u & 1)] : sw[4 + 2 * g + (u & 1)];
                }

                // O^T += V^T * P^T ; V^T frags from LDS (swizzled)
                __builtin_amdgcn_s_setprio(1);
#pragma unroll
                for (int dt = 0; dt < 4; ++dt) {
                    const u32 vrow = (u32)(dt * 32 + ql);
                    const u32 vsw = (vrow & 7) << 4;
                    bf16x8 v0 = *(const bf16x8*)(lVb + vrow * 128 + (((u32)(s * 64 + g * 16)) ^ vsw));
                    bf16x8 v1 = *(const bf16x8*)(lVb + vrow * 128 + (((u32)(s * 64 + 32 + g * 16)) ^ vsw));
                    acc[dt] = __builtin_amdgcn_mfma_f32_32x32x16_bf16(v0, pf0.v, acc[dt], 0, 0, 0);
                    acc[dt] = __builtin_amdgcn_mfma_f32_32x32x16_bf16(v1, pf1.v, acc[dt], 0, 0, 0);
                }
                __builtin_amdgcn_s_setprio(0);
            }
        }
        __syncthreads();   // stage(buf^1) landed; all reads of buf done
        buf ^= 1;
    }

    const float inv_l = 1.0f / l_run;
    u16* orow = obuf + (rowbase + q) * 2048 + h * 128;
#pragma unroll
    for (int dt = 0; dt < 4; ++dt) {
#pragma unroll
        for (int rr = 0; rr < 4; ++rr) {
            int d0 = dt * 32 + rr * 8 + g * 4;   // d' = (r&3)+8*(r>>2)+4g+32dt
            int r0 = rr * 4;
            u32 w0 = pack_bf2(acc[dt][r0] * inv_l,     acc[dt][r0 + 1] * inv_l);
            u32 w1 = pack_bf2(acc[dt][r0 + 2] * inv_l, acc[dt][r0 + 3] * inv_l);
            *(u32*)(orow + d0)     = w0;
            *(u32*)(orow + d0 + 2) = w1;
        }
    }
}

extern "C" void kernel_launch(void* const* d_in, const int* in_sizes, int n_in,
                              void* d_out, int out_size, void* d_ws, size_t ws_size,
                              hipStream_t stream) {
    (void)in_sizes; (void)n_in; (void)out_size; (void)ws_size;
    const float* x    = (const float*)d_in[0];
    const float* Wqkv = (const float*)d_in[1];
    const float* bqkv = (const float*)d_in[2];
    const float* Wout = (const float*)d_in[3];
    const float* bout = (const float*)d_in[4];

    char* ws = (char*)d_ws;
    u16* xb  = (u16*)ws;                        // [4096,2048] bf16, 16 MB
    u16* wqb = (u16*)(ws + (size_t)16777216);   // [6144,2048] bf16, 24 MB
    u16* qkv = (u16*)(ws + (size_t)41943040);   // [4096,6144] bf16, 48 MB
    u16* ob  = xb;   // attention out reuses xb (x dead after GEMM1)
    u16* vtb = wqb;  // V^T [32,128,2048] bf16 16 MB reuses wqb
    u16* wob = wqb;  // W_out bf16 reuses wqb again (vtb dead after attn)

    cvt_f32_bf16<<<2048, 256, 0, stream>>>(x, xb, 8388608L / 8);
    cvt_f32_bf16<<<2048, 256, 0, stream>>>(Wqkv, wqb, 12582912L / 8);
    gemm_nt<1><<<1536, 256, 0, stream>>>(xb, wqb, bqkv, qkv, 2048, 6144, 5);
    transpose_v<<<2048, 256, 0, stream>>>(qkv, vtb);
    attn_fwd<<<512, 256, 0, stream>>>(qkv, vtb, ob);
    cvt_f32_bf16<<<2048, 256, 0, stream>>>(Wout, wob, 4194304L / 8);
    gemm_nt<0><<<512, 256, 0, stream>>>(ob, wob, bout, d_out, 2048, 2048, 5);
}